// Round 10
// baseline (404.284 us; speedup 1.0000x reference)
//
#include <hip/hip_runtime.h>

#define N_DST 25000
#define E_NUM 400000

typedef __bf16 bf16x8 __attribute__((ext_vector_type(8)));
typedef __bf16 bf16x4 __attribute__((ext_vector_type(4)));
typedef float  f32x4  __attribute__((ext_vector_type(4)));

__device__ __forceinline__ float fast_cos(float x) {
  float r = x * 0.15915494309189535f;
  r = r - floorf(r);
  return __builtin_amdgcn_cosf(r);
}

// pack W into frag-contiguous bf16: out[fid*64+lane] = W[n][g*8..g*8+7]
__device__ __forceinline__ void pack_frag(const float* __restrict__ W0,
    const float* __restrict__ W1, int stride, int NC, int idx, __bf16* __restrict__ out) {
  int lane = idx & 63, fid = idx >> 6;
  int nfw = NC >> 6;
  int perks = nfw << 2;
  int ks = fid / perks, rem = fid - ks * perks;
  int w = rem / nfw, nf = rem - w * nfw;
  int n = w * (NC >> 2) + nf * 16 + (lane & 15);
  int g = (ks << 2) + (lane >> 4);
  const float* src = (W1 && n >= 128) ? (W1 + (size_t)(n - 128) * stride)
                                      : (W0 + (size_t)n * stride);
  const float4* s4 = reinterpret_cast<const float4*>(src + g * 8);
  float4 lo = s4[0], hi = s4[1];
  bf16x8 b;
  b[0]=(__bf16)lo.x; b[1]=(__bf16)lo.y; b[2]=(__bf16)lo.z; b[3]=(__bf16)lo.w;
  b[4]=(__bf16)hi.x; b[5]=(__bf16)hi.y; b[6]=(__bf16)hi.z; b[7]=(__bf16)hi.w;
  reinterpret_cast<bf16x8*>(out)[idx] = b;
}

// one kernel: cq + 3 B-repacks + edge counting
__global__ __launch_bounds__(256) void prep_kernel(
    const float* __restrict__ Wq, const float* __restrict__ bq, const float* __restrict__ tb,
    const float* __restrict__ Wk, const float* __restrict__ Wv, const float* __restrict__ Wout,
    const int* __restrict__ dsti,
    float* __restrict__ cq, __bf16* __restrict__ Bq_kv, __bf16* __restrict__ Bq_q,
    __bf16* __restrict__ Bq_out, int* __restrict__ counts) {
  int b = blockIdx.x, tid = threadIdx.x;
  if (b == 0) {
    if (tid < 128) {
      float s = bq[tid];
      for (int j = 0; j < 128; ++j) s += cosf(tb[j]) * Wq[tid * 256 + 128 + j];
      cq[tid] = s;
    }
    return;
  }
  b -= 1;
  if (b < 48) { pack_frag(Wk, Wv, 384, 256, b * 256 + tid, Bq_kv); return; }
  b -= 48;
  if (b < 8)  { pack_frag(Wq, nullptr, 256, 128, b * 256 + tid, Bq_q); return; }
  b -= 8;
  if (b < 16) { pack_frag(Wout, nullptr, 256, 128, b * 256 + tid, Bq_out); return; }
  b -= 16;
  int e = b * 256 + tid;
  if (e < E_NUM) atomicAdd(&counts[dsti[e]], 1);
}

// ---------------- 3-phase parallel scan over counts ----------------
__global__ __launch_bounds__(1024) void scanA_kernel(const int* __restrict__ counts,
    int* __restrict__ bsum) {
  __shared__ int wsum[16];
  int tid = threadIdx.x;
  int idx = blockIdx.x * 1024 + tid;
  int s = (idx < N_DST) ? counts[idx] : 0;
#pragma unroll
  for (int o = 32; o; o >>= 1) s += __shfl_xor(s, o);
  if ((tid & 63) == 0) wsum[tid >> 6] = s;
  __syncthreads();
  if (tid == 0) {
    int t = 0;
#pragma unroll
    for (int i = 0; i < 16; ++i) t += wsum[i];
    bsum[blockIdx.x] = t;
  }
}

__global__ void scanB_kernel(const int* __restrict__ bsum, int* __restrict__ boff) {
  if (threadIdx.x == 0) {
    int c = 0;
    for (int i = 0; i < 25; ++i) { boff[i] = c; c += bsum[i]; }
    boff[25] = c;
  }
}

__global__ __launch_bounds__(1024) void scanC_kernel(const int* __restrict__ counts,
    const int* __restrict__ boff, int* __restrict__ offs, int* __restrict__ cursor) {
  __shared__ int wpart[16];
  int tid = threadIdx.x, lane = tid & 63, wid = tid >> 6;
  int idx = blockIdx.x * 1024 + tid;
  int x = (idx < N_DST) ? counts[idx] : 0;
  int incl = x;
#pragma unroll
  for (int o = 1; o < 64; o <<= 1) {
    int y = __shfl_up(incl, o);
    if (lane >= o) incl += y;
  }
  if (lane == 63) wpart[wid] = incl;
  __syncthreads();
  if (wid == 0) {
    int v = (lane < 16) ? wpart[lane] : 0;
    int s = v;
#pragma unroll
    for (int o = 1; o < 16; o <<= 1) {
      int y = __shfl_up(s, o);
      if (lane >= o) s += y;
    }
    if (lane < 16) wpart[lane] = s;
  }
  __syncthreads();
  int woff = (wid > 0) ? wpart[wid - 1] : 0;
  int v = boff[blockIdx.x] + woff + incl - x;
  if (idx < N_DST) {
    offs[idx] = v;
    cursor[idx] = v;
  }
  if (idx == N_DST - 1) offs[N_DST] = v + x;
}

// dst-sorted edge list: elist[p] = e, dsts[p] = dst
__global__ __launch_bounds__(256) void fill_kernel(const int* __restrict__ dsti,
    int* __restrict__ cursor, int* __restrict__ elist, int* __restrict__ dsts) {
  int e = blockIdx.x * 256 + threadIdx.x;
  if (e < E_NUM) {
    int d = dsti[e];
    int p = atomicAdd(&cursor[d], 1);
    elist[p] = e;
    dsts[p] = d;
  }
}

// ============ KV kernel: SORTED gather + asm issue-early staging + reg-cos ============
// Blocks own 64 dst-sorted edges: input rows gathered (512B chunks, coalesced within
// row), V/score written SEQUENTIALLY in sorted space; Q reads L1-hot (few distinct
// dsts per block). Phases {src0,src1,edge0,edge1}: inline-asm global_load_dwordx4
// (cannot be sunk by regalloc) -> ktile -> vmcnt(0) -> cvt+LDS write -> barrier.
// Time-cos K-steps computed per-lane straight into MFMA A-fragments.
__global__ __launch_bounds__(256, 4) void kv_kernel(
    const float* __restrict__ node_h, const float* __restrict__ edge_f,
    const float* __restrict__ dtp, const float* __restrict__ tw, const float* __restrict__ tb,
    const __bf16* __restrict__ Bq,
    const float* __restrict__ bk, const float* __restrict__ bv,
    const int* __restrict__ elist, const int* __restrict__ dsts,
    const float* __restrict__ Qn,
    __bf16* __restrict__ Vout, float* __restrict__ score)
{
  __shared__ __align__(16) char Ab[2][8192];    // [2][64 rows][128 B] bf16, XOR-swizzled
  __shared__ __align__(16) char Vlds[16384];    // V bounce [64][256 B] bf16, swizzled
  __shared__ int Elds[64];
  __shared__ int Dlds[64];
  __shared__ float dts[64];
  __shared__ float twl[128];
  __shared__ float tbl[128];

  const int tid = threadIdx.x;
  const int e0 = blockIdx.x * 64;
  const int lane = tid & 63;
  const int w = tid >> 6;
  const int lrow = lane & 15;
  const int lk = lane >> 4;
  const int aswz = (lrow & 7) << 4;

  if (tid < 64) {
    int e = elist[e0 + tid];
    Elds[tid] = e;
    Dlds[tid] = dsts[e0 + tid];
    dts[tid] = dtp[e];
  } else if (tid < 192) {
    int j = tid - 64;
    twl[j] = tw[j];
    tbl[j] = tb[j];
  }
  __syncthreads();

  // staging: thread covers gathered row srow=tid>>2, 64B chunk sq=tid&3
  const int srow = tid >> 2;
  const int sq = tid & 3;
  const int eidx = Elds[srow];
  const char* sR = (const char*)(node_h + (size_t)(N_DST + eidx) * 128) + sq * 64;
  const char* eR = (const char*)(edge_f + (size_t)eidx * 128) + sq * 64;
  float4 st0, st1, st2, st3;

  auto issueL = [&](int t) {
    const char* p = (t < 2) ? (sR + t * 256) : (eR + (t - 2) * 256);
    asm volatile(
        "global_load_dwordx4 %0, %4, off\n\t"
        "global_load_dwordx4 %1, %4, off offset:16\n\t"
        "global_load_dwordx4 %2, %4, off offset:32\n\t"
        "global_load_dwordx4 %3, %4, off offset:48"
        : "=&v"(st0), "=&v"(st1), "=&v"(st2), "=&v"(st3)
        : "v"(p));
  };
  auto waitL = [&]() {
    asm volatile("s_waitcnt vmcnt(0)" ::: "memory");
    __builtin_amdgcn_sched_barrier(0);
  };
  auto writeA = [&](char* buf) {
    char* rb = buf + srow * 128;
    int sw = (srow & 7) << 4;
    float4 vv[4] = {st0, st1, st2, st3};
#pragma unroll
    for (int i = 0; i < 4; ++i) {
      bf16x4 b;
      b[0]=(__bf16)vv[i].x; b[1]=(__bf16)vv[i].y; b[2]=(__bf16)vv[i].z; b[3]=(__bf16)vv[i].w;
      *reinterpret_cast<bf16x4*>(rb + ((sq * 32 + i * 8) ^ sw)) = b;
    }
  };

  f32x4 acc[4][4];
#pragma unroll
  for (int mf = 0; mf < 4; ++mf)
#pragma unroll
    for (int nf = 0; nf < 4; ++nf)
      acc[mf][nf] = (f32x4){0.f, 0.f, 0.f, 0.f};

  const bf16x8* __restrict__ Bw = reinterpret_cast<const bf16x8*>(Bq) + (size_t)(w * 4) * 64 + lane;

  auto ktileM = [&](const char* buf, int t) {   // 2 K32 steps from a 64-col LDS tile
#pragma unroll
    for (int ks = 0; ks < 2; ++ks) {
      int K32 = t * 2 + ks;
      bf16x8 b[4];
#pragma unroll
      for (int nf = 0; nf < 4; ++nf)
        b[nf] = Bw[((size_t)K32 * 16 + nf) * 64];
      bf16x8 a[4];
#pragma unroll
      for (int mf = 0; mf < 4; ++mf)
        a[mf] = *reinterpret_cast<const bf16x8*>(
            buf + (mf * 16 + lrow) * 128 + ((ks * 64 + lk * 16) ^ aswz));
#pragma unroll
      for (int nf = 0; nf < 4; ++nf)
#pragma unroll
        for (int mf = 0; mf < 4; ++mf)
          acc[mf][nf] = __builtin_amdgcn_mfma_f32_16x16x32_bf16(a[mf], b[nf], acc[mf][nf], 0, 0, 0);
    }
  };

  float dv[4];
#pragma unroll
  for (int mf = 0; mf < 4; ++mf) dv[mf] = dts[mf * 16 + lrow];

  auto ktileC = [&](int cs) {                   // time-cos K32 step, A-frag in regs
    int K32 = 8 + cs;
    int J = cs * 32 + lk * 8;
    f32x4 w0 = *reinterpret_cast<const f32x4*>(twl + J);
    f32x4 w1 = *reinterpret_cast<const f32x4*>(twl + J + 4);
    f32x4 c0 = *reinterpret_cast<const f32x4*>(tbl + J);
    f32x4 c1 = *reinterpret_cast<const f32x4*>(tbl + J + 4);
    bf16x8 b[4];
#pragma unroll
    for (int nf = 0; nf < 4; ++nf)
      b[nf] = Bw[((size_t)K32 * 16 + nf) * 64];
#pragma unroll
    for (int mf = 0; mf < 4; ++mf) {
      float d = dv[mf];
      bf16x8 a;
#pragma unroll
      for (int j = 0; j < 4; ++j) {
        a[j] = (__bf16)fast_cos(d * w0[j] + c0[j]);
        a[4 + j] = (__bf16)fast_cos(d * w1[j] + c1[j]);
      }
#pragma unroll
      for (int nf = 0; nf < 4; ++nf)
        acc[mf][nf] = __builtin_amdgcn_mfma_f32_16x16x32_bf16(a, b[nf], acc[mf][nf], 0, 0, 0);
    }
  };

  // ---- pipeline: issue(t+1) -> ktile(t) -> vmcnt -> write(t+1) -> barrier
  issueL(0);
  waitL();
  writeA(Ab[0]);
  __syncthreads();
  issueL(1);
  ktileM(Ab[0], 0);
  waitL();
  writeA(Ab[1]);
  __syncthreads();
  issueL(2);
  ktileM(Ab[1], 1);
  waitL();
  writeA(Ab[0]);
  __syncthreads();
  issueL(3);
  ktileM(Ab[0], 2);
  waitL();
  writeA(Ab[1]);
  __syncthreads();
  ktileM(Ab[1], 3);
  ktileC(0); ktileC(1); ktileC(2); ktileC(3);

  // ---- epilogue: scores from regs (waves 0,1; Q L1-hot via sorted dsts),
  //      V via LDS bounce (waves 2,3); both written SEQUENTIALLY in sorted space.
  if (w >= 2) {
#pragma unroll
    for (int nf = 0; nf < 4; ++nf) {
      int vcol = (w - 2) * 64 + nf * 16 + lrow;
      float bb = bv[vcol];
#pragma unroll
      for (int mf = 0; mf < 4; ++mf) {
#pragma unroll
        for (int r = 0; r < 4; ++r) {
          int row = mf * 16 + lk * 4 + r;
          *reinterpret_cast<__bf16*>(Vlds + row * 256 + ((vcol * 2) ^ ((row & 7) << 4))) =
              (__bf16)(acc[mf][nf][r] + bb);
        }
      }
    }
  } else {
    float bkv[4];
#pragma unroll
    for (int nf = 0; nf < 4; ++nf) bkv[nf] = bk[w * 64 + nf * 16 + lrow];
#pragma unroll
    for (int mf = 0; mf < 4; ++mf) {
#pragma unroll
      for (int r = 0; r < 4; ++r) {
        int row = mf * 16 + lk * 4 + r;
        const float* qrow = Qn + ((size_t)Dlds[row] << 7) + w * 64;
        float s = 0.f;
#pragma unroll
        for (int nf = 0; nf < 4; ++nf)
          s += (acc[mf][nf][r] + bkv[nf]) * qrow[nf * 16 + lrow];
        s += __shfl_xor(s, 1);
        s += __shfl_xor(s, 2);
        s += __shfl_xor(s, 4);
        s += __shfl_xor(s, 8);
        if (lrow == 0) {
          s = (s >= 0.f) ? s : 0.2f * s;
          score[((size_t)(e0 + row) << 1) + w] = s;
        }
      }
    }
  }
  __syncthreads();
#pragma unroll
  for (int i = 0; i < 4; ++i) {
    int c = tid + i * 256;
    int r = c >> 4, cb = (c & 15) << 4;
    bf16x8 vv = *reinterpret_cast<const bf16x8*>(Vlds + r * 256 + (cb ^ ((r & 7) << 4)));
    *reinterpret_cast<bf16x8*>(Vout + (((size_t)(e0 + r)) << 7) + (c & 15) * 8) = vv;
  }
}

// ---------------- Q projection: Qn = tgt @ Wq1^T + cq (K=128) ----------------
__global__ __launch_bounds__(256, 4) void q_kernel(
    const float* __restrict__ A0, const __bf16* __restrict__ Bq,
    const float* __restrict__ cq, float* __restrict__ outF)
{
  __shared__ __align__(16) char Abuf[64 * 256];
  const int tid = threadIdx.x;
  const int e0 = blockIdx.x * 64;
  const int nv = min(64, N_DST - e0);
  const int srow = tid >> 5;
  const int sc4 = (tid & 31) << 2;
  const int lane = tid & 63;
  const int w = tid >> 6;
  const int nbase = w * 32;
  const int lrow = lane & 15;
  const int lk = lane >> 4;
  const int aswz = (lrow & 7) << 4;
  const bf16x8* __restrict__ Bw =
      reinterpret_cast<const bf16x8*>(Bq) + (size_t)(w * 2) * 64 + lane;

  f32x4 acc[4][2];
#pragma unroll
  for (int mf = 0; mf < 4; ++mf)
#pragma unroll
    for (int nf = 0; nf < 2; ++nf)
      acc[mf][nf] = (f32x4){0.f, 0.f, 0.f, 0.f};

#pragma unroll
  for (int i = 0; i < 8; ++i) {
    int r = srow + i * 8;
    float4 v = (r < nv) ? *reinterpret_cast<const float4*>(A0 + (size_t)(e0 + r) * 128 + sc4)
                        : make_float4(0.f, 0.f, 0.f, 0.f);
    bf16x4 b;
    b[0]=(__bf16)v.x; b[1]=(__bf16)v.y; b[2]=(__bf16)v.z; b[3]=(__bf16)v.w;
    *reinterpret_cast<bf16x4*>(Abuf + r * 256 + ((sc4 * 2) ^ ((r & 7) << 4))) = b;
  }
  __syncthreads();

#pragma unroll
  for (int ks = 0; ks < 4; ++ks) {
    bf16x8 b[2];
#pragma unroll
    for (int nf = 0; nf < 2; ++nf)
      b[nf] = Bw[((size_t)ks * 8 + nf) * 64];
    bf16x8 a[4];
#pragma unroll
    for (int mf = 0; mf < 4; ++mf)
      a[mf] = *reinterpret_cast<const bf16x8*>(
          Abuf + (mf * 16 + lrow) * 256 + (((ks * 32 + lk * 8) * 2) ^ aswz));
#pragma unroll
    for (int nf = 0; nf < 2; ++nf)
#pragma unroll
      for (int mf = 0; mf < 4; ++mf)
        acc[mf][nf] = __builtin_amdgcn_mfma_f32_16x16x32_bf16(a[mf], b[nf], acc[mf][nf], 0, 0, 0);
  }

#pragma unroll
  for (int nf = 0; nf < 2; ++nf) {
    int col = nbase + nf * 16 + lrow;
    float bb = cq[col];
#pragma unroll
    for (int mf = 0; mf < 4; ++mf) {
#pragma unroll
      for (int r = 0; r < 4; ++r) {
        int row = mf * 16 + lk * 4 + r;
        if (row < nv)
          outF[(size_t)(e0 + row) * 128 + col] = acc[mf][nf][r] + bb;
      }
    }
  }
}

// ======== out kernel: fused {per-dst softmax+PV agg} + out-GEMM + relu + LN ========
// Block owns 64 dsts. Wave w aggregates dsts w*16..w*16+15 (sequential CSR reads),
// writing h rows as bf16 straight into the GEMM A-tile (LDS). tgt tile staged
// normally. Then K=256 MFMA + fused relu/LN epilogue.
__global__ __launch_bounds__(256, 4) void out_kernel(
    const float* __restrict__ node_h, const int* __restrict__ offs,
    const float* __restrict__ score, const __bf16* __restrict__ V,
    const float* __restrict__ gamma, const float* __restrict__ beta,
    const __bf16* __restrict__ Bq, const float* __restrict__ bout,
    float* __restrict__ outp)
{
  __shared__ __align__(16) char Ah[64 * 256];   // h tile bf16 swizzled
  __shared__ __align__(16) char At[64 * 256];   // tgt tile bf16 swizzled
  const int tid = threadIdx.x;
  const int d0 = blockIdx.x * 64;
  const int nv = min(64, N_DST - d0);
  const int lane = tid & 63;
  const int w = tid >> 6;
  const int lrow = lane & 15;
  const int lk = lane >> 4;
  const int aswz = (lrow & 7) << 4;

  // stage tgt tile
  {
    int srow = tid >> 5;
    int sc4 = (tid & 31) << 2;
#pragma unroll
    for (int i = 0; i < 8; ++i) {
      int r = srow + i * 8;
      float4 v = (r < nv) ? *reinterpret_cast<const float4*>(node_h + (size_t)(d0 + r) * 128 + sc4)
                          : make_float4(0.f, 0.f, 0.f, 0.f);
      bf16x4 b;
      b[0]=(__bf16)v.x; b[1]=(__bf16)v.y; b[2]=(__bf16)v.z; b[3]=(__bf16)v.w;
      *reinterpret_cast<bf16x4*>(At + r * 256 + ((sc4 * 2) ^ ((r & 7) << 4))) = b;
    }
  }

  // aggregate: wave w handles 16 dsts
  for (int k = 0; k < 16; ++k) {
    int row = w * 16 + k;
    int d = d0 + row;
    if (d < N_DST) {
      int beg = offs[d], end = offs[d + 1];
      int n = end - beg;
      float m0 = -3.0e38f, m1 = -3.0e38f;
      for (int i = lane; i < n; i += 64) {
        float2 sc = *reinterpret_cast<const float2*>(score + 2 * (size_t)(beg + i));
        m0 = fmaxf(m0, sc.x); m1 = fmaxf(m1, sc.y);
      }
#pragma unroll
      for (int o = 32; o; o >>= 1) {
        m0 = fmaxf(m0, __shfl_xor(m0, o));
        m1 = fmaxf(m1, __shfl_xor(m1, o));
      }
      float s0 = 0.f, s1 = 0.f;
      for (int i = lane; i < n; i += 64) {
        float2 sc = *reinterpret_cast<const float2*>(score + 2 * (size_t)(beg + i));
        s0 += __expf(sc.x - m0); s1 += __expf(sc.y - m1);
      }
#pragma unroll
      for (int o = 32; o; o >>= 1) {
        s0 += __shfl_xor(s0, o);
        s1 += __shfl_xor(s1, o);
      }
      float inv0 = (n > 0) ? 1.f / s0 : 0.f;
      float inv1 = (n > 0) ? 1.f / s1 : 0.f;
      int q = lane >> 4, j = lane & 15;
      int hsel = j >> 3;
      float acc[8];
#pragma unroll
      for (int k2 = 0; k2 < 8; ++k2) acc[k2] = 0.f;
      for (int i0 = 0; i0 < n; i0 += 4) {
        int i = i0 + q;
        if (i < n) {
          size_t p = beg + i;
          float2 sc = *reinterpret_cast<const float2*>(score + 2 * p);
          float wgt = hsel ? __expf(sc.y - m1) * inv1 : __expf(sc.x - m0) * inv0;
          bf16x8 v = *reinterpret_cast<const bf16x8*>(V + (p << 7) + j * 8);
#pragma unroll
          for (int k2 = 0; k2 < 8; ++k2) acc[k2] += wgt * (float)v[k2];
        }
      }
#pragma unroll
      for (int k2 = 0; k2 < 8; ++k2) {
        acc[k2] += __shfl_xor(acc[k2], 16);
        acc[k2] += __shfl_xor(acc[k2], 32);
      }
      if (q == 0) {   // lanes 0..15 hold cols j*8..j*8+7
        bf16x8 hb;
#pragma unroll
        for (int k2 = 0; k2 < 8; ++k2) hb[k2] = (__bf16)acc[k2];
        *reinterpret_cast<bf16x8*>(Ah + row * 256 + ((j * 16) ^ ((row & 7) << 4))) = hb;
      }
    }
  }
  __syncthreads();

  // GEMM: K=256 (cols 0-127 = h from Ah, 128-255 = tgt from At)
  const bf16x8* __restrict__ Bw =
      reinterpret_cast<const bf16x8*>(Bq) + (size_t)(w * 2) * 64 + lane;
  f32x4 acc[4][2];
#pragma unroll
  for (int mf = 0; mf < 4; ++mf)
#pragma unroll
    for (int nf = 0; nf < 2; ++nf)
      acc[mf][nf] = (f32x4){0.f, 0.f, 0.f, 0.f};

#pragma unroll
  for (int t = 0; t < 2; ++t) {
    const char* buf = (t == 0) ? Ah : At;
#pragma unroll
    for (int ks = 0; ks < 4; ++ks) {
      bf16x8 b[2];
#pragma unroll
      for (int nf = 0; nf < 2; ++nf)
        b[nf] = Bw[((size_t)(t * 4 + ks) * 8 + nf) * 64];
      bf16x8 a[4];
#pragma unroll
      for (int mf = 0; mf < 4; ++mf)
        a[mf] = *reinterpret_cast<const bf16x8*>(
            buf + (mf * 16 + lrow) * 256 + (((ks * 32 + lk * 8) * 2) ^ aswz));
#pragma unroll
      for (int nf = 0; nf < 2; ++nf)
#pragma unroll
        for (int mf = 0; mf < 4; ++mf)
          acc[mf][nf] = __builtin_amdgcn_mfma_f32_16x16x32_bf16(a[mf], b[nf], acc[mf][nf], 0, 0, 0);
    }
  }

  // fused relu + layernorm epilogue
  const int nbase = w * 32;
  float vals[2][4][4];
#pragma unroll
  for (int nf = 0; nf < 2; ++nf) {
    float bb = bout[nbase + nf * 16 + lrow];
#pragma unroll
    for (int mf = 0; mf < 4; ++mf)
#pragma unroll
      for (int r = 0; r < 4; ++r)
        vals[nf][mf][r] = fmaxf(acc[mf][nf][r] + bb, 0.f);
  }
  __syncthreads();
  float* sums = reinterpret_cast<float*>(Ah);
  float* sqs  = reinterpret_cast<float*>(Ah) + 256;
  float* stats = reinterpret_cast<float*>(Ah) + 512;
#pragma unroll
  for (int mf = 0; mf < 4; ++mf) {
#pragma unroll
    for (int r = 0; r < 4; ++r) {
      float s1 = vals[0][mf][r] + vals[1][mf][r];
      float s2 = vals[0][mf][r] * vals[0][mf][r] + vals[1][mf][r] * vals[1][mf][r];
#pragma unroll
      for (int o = 1; o < 16; o <<= 1) {
        s1 += __shfl_xor(s1, o);
        s2 += __shfl_xor(s2, o);
      }
      if (lrow == 0) {
        int row = mf * 16 + lk * 4 + r;
        sums[w * 64 + row] = s1;
        sqs[w * 64 + row] = s2;
      }
    }
  }
  __syncthreads();
  if (tid < 64) {
    float s = sums[tid] + sums[64 + tid] + sums[128 + tid] + sums[192 + tid];
    float q = sqs[tid] + sqs[64 + tid] + sqs[128 + tid] + sqs[192 + tid];
    float mean = s * (1.f / 128.f);
    float var = q * (1.f / 128.f) - mean * mean;
    stats[tid * 2] = mean;
    stats[tid * 2 + 1] = rsqrtf(var + 1e-5f);
  }
  __syncthreads();
#pragma unroll
  for (int nf = 0; nf < 2; ++nf) {
    int col = nbase + nf * 16 + lrow;
    float g = gamma[col], bC = beta[col];
#pragma unroll
    for (int mf = 0; mf < 4; ++mf) {
#pragma unroll
      for (int r = 0; r < 4; ++r) {
        int row = mf * 16 + lk * 4 + r;
        if (row < nv) {
          float mean = stats[row * 2], rs = stats[row * 2 + 1];
          outp[(size_t)(d0 + row) * 128 + col] = (vals[nf][mf][r] - mean) * rs * g + bC;
        }
      }
    }
  }
}

extern "C" void kernel_launch(void* const* d_in, const int* in_sizes, int n_in,
                              void* d_out, int out_size, void* d_ws, size_t ws_size,
                              hipStream_t stream) {
  (void)in_sizes; (void)n_in; (void)out_size; (void)ws_size;
  const float* node_h = (const float*)d_in[0];
  const float* edge_f = (const float*)d_in[1];
  const float* dtp    = (const float*)d_in[2];
  const int*   dsti   = (const int*)d_in[3];
  const float* tw     = (const float*)d_in[4];
  const float* tb     = (const float*)d_in[5];
  const float* Wq     = (const float*)d_in[6];
  const float* bq     = (const float*)d_in[7];
  const float* Wk     = (const float*)d_in[8];
  const float* bk     = (const float*)d_in[9];
  const float* Wv     = (const float*)d_in[10];
  const float* bv     = (const float*)d_in[11];
  const float* Wout   = (const float*)d_in[12];
  const float* bout   = (const float*)d_in[13];
  const float* gamma  = (const float*)d_in[14];
  const float* beta   = (const float*)d_in[15];
  float* outp = (float*)d_out;

  size_t off = 0;
  auto take = [&](size_t nbytes) -> void* {
    void* r = (char*)d_ws + off;
    off += (nbytes + 255) & ~(size_t)255;
    return r;
  };
  __bf16* Bq_kv  = (__bf16*)take((size_t)12288 * 16);
  __bf16* Bq_q   = (__bf16*)take((size_t)2048 * 16);
  __bf16* Bq_out = (__bf16*)take((size_t)4096 * 16);
  float*  cq     = (float*)take(128 * 4);
  float*  Qn     = (float*)take((size_t)N_DST * 128 * 4);
  __bf16* Vbuf   = (__bf16*)take((size_t)E_NUM * 128 * 2);
  float*  score  = (float*)take((size_t)E_NUM * 2 * 4);
  int*    counts = (int*)take((size_t)N_DST * 4);
  int*    offs   = (int*)take((size_t)(N_DST + 1) * 4);
  int*    cursor = (int*)take((size_t)N_DST * 4);
  int*    elist  = (int*)take((size_t)E_NUM * 4);
  int*    dsts   = (int*)take((size_t)E_NUM * 4);
  int*    bsum   = (int*)take(32 * 4);
  int*    boff   = (int*)take(32 * 4);

  hipMemsetAsync(counts, 0, (size_t)N_DST * 4, stream);

  const int count_blocks = (E_NUM + 255) / 256;
  prep_kernel<<<1 + 48 + 8 + 16 + count_blocks, 256, 0, stream>>>(
      Wq, bq, tb, Wk, Wv, Wout, dsti, cq, Bq_kv, Bq_q, Bq_out, counts);

  q_kernel<<<(N_DST + 63) / 64, 256, 0, stream>>>(node_h, Bq_q, cq, Qn);

  scanA_kernel<<<25, 1024, 0, stream>>>(counts, bsum);
  scanB_kernel<<<1, 64, 0, stream>>>(bsum, boff);
  scanC_kernel<<<25, 1024, 0, stream>>>(counts, boff, offs, cursor);
  fill_kernel<<<count_blocks, 256, 0, stream>>>(dsti, cursor, elist, dsts);

  kv_kernel<<<E_NUM / 64, 256, 0, stream>>>(node_h, edge_f, dtp, tw, tb,
      Bq_kv, bk, bv, elist, dsts, Qn, Vbuf, score);

  out_kernel<<<(N_DST + 63) / 64, 256, 0, stream>>>(node_h, offs, score, Vbuf,
      gamma, beta, Bq_out, bout, outp);
}

// Round 11
// 328.421 us; speedup vs baseline: 1.2310x; 1.2310x over previous
//
#include <hip/hip_runtime.h>

#define N_DST 25000
#define E_NUM 400000

typedef __bf16 bf16x8 __attribute__((ext_vector_type(8)));
typedef __bf16 bf16x4 __attribute__((ext_vector_type(4)));
typedef float  f32x4  __attribute__((ext_vector_type(4)));

__device__ __forceinline__ float fast_cos(float x) {
  float r = x * 0.15915494309189535f;
  r = r - floorf(r);
  return __builtin_amdgcn_cosf(r);
}

// pack W into frag-contiguous bf16: out[fid*64+lane] = W[n][g*8..g*8+7]
__device__ __forceinline__ void pack_frag(const float* __restrict__ W0,
    const float* __restrict__ W1, int stride, int NC, int idx, __bf16* __restrict__ out) {
  int lane = idx & 63, fid = idx >> 6;
  int nfw = NC >> 6;
  int perks = nfw << 2;
  int ks = fid / perks, rem = fid - ks * perks;
  int w = rem / nfw, nf = rem - w * nfw;
  int n = w * (NC >> 2) + nf * 16 + (lane & 15);
  int g = (ks << 2) + (lane >> 4);
  const float* src = (W1 && n >= 128) ? (W1 + (size_t)(n - 128) * stride)
                                      : (W0 + (size_t)n * stride);
  const float4* s4 = reinterpret_cast<const float4*>(src + g * 8);
  float4 lo = s4[0], hi = s4[1];
  bf16x8 b;
  b[0]=(__bf16)lo.x; b[1]=(__bf16)lo.y; b[2]=(__bf16)lo.z; b[3]=(__bf16)lo.w;
  b[4]=(__bf16)hi.x; b[5]=(__bf16)hi.y; b[6]=(__bf16)hi.z; b[7]=(__bf16)hi.w;
  reinterpret_cast<bf16x8*>(out)[idx] = b;
}

// one kernel: cq + 3 B-repacks + edge counting
__global__ __launch_bounds__(256) void prep_kernel(
    const float* __restrict__ Wq, const float* __restrict__ bq, const float* __restrict__ tb,
    const float* __restrict__ Wk, const float* __restrict__ Wv, const float* __restrict__ Wout,
    const int* __restrict__ dsti,
    float* __restrict__ cq, __bf16* __restrict__ Bq_kv, __bf16* __restrict__ Bq_q,
    __bf16* __restrict__ Bq_out, int* __restrict__ counts) {
  int b = blockIdx.x, tid = threadIdx.x;
  if (b == 0) {
    if (tid < 128) {
      float s = bq[tid];
      for (int j = 0; j < 128; ++j) s += cosf(tb[j]) * Wq[tid * 256 + 128 + j];
      cq[tid] = s;
    }
    return;
  }
  b -= 1;
  if (b < 48) { pack_frag(Wk, Wv, 384, 256, b * 256 + tid, Bq_kv); return; }
  b -= 48;
  if (b < 8)  { pack_frag(Wq, nullptr, 256, 128, b * 256 + tid, Bq_q); return; }
  b -= 8;
  if (b < 16) { pack_frag(Wout, nullptr, 256, 128, b * 256 + tid, Bq_out); return; }
  b -= 16;
  int e = b * 256 + tid;
  if (e < E_NUM) atomicAdd(&counts[dsti[e]], 1);
}

// ---------------- 3-phase parallel scan over counts ----------------
__global__ __launch_bounds__(1024) void scanA_kernel(const int* __restrict__ counts,
    int* __restrict__ bsum) {
  __shared__ int wsum[16];
  int tid = threadIdx.x;
  int idx = blockIdx.x * 1024 + tid;
  int s = (idx < N_DST) ? counts[idx] : 0;
#pragma unroll
  for (int o = 32; o; o >>= 1) s += __shfl_xor(s, o);
  if ((tid & 63) == 0) wsum[tid >> 6] = s;
  __syncthreads();
  if (tid == 0) {
    int t = 0;
#pragma unroll
    for (int i = 0; i < 16; ++i) t += wsum[i];
    bsum[blockIdx.x] = t;
  }
}

__global__ void scanB_kernel(const int* __restrict__ bsum, int* __restrict__ boff) {
  if (threadIdx.x == 0) {
    int c = 0;
    for (int i = 0; i < 25; ++i) { boff[i] = c; c += bsum[i]; }
    boff[25] = c;
  }
}

__global__ __launch_bounds__(1024) void scanC_kernel(const int* __restrict__ counts,
    const int* __restrict__ boff, int* __restrict__ offs, int* __restrict__ cursor) {
  __shared__ int wpart[16];
  int tid = threadIdx.x, lane = tid & 63, wid = tid >> 6;
  int idx = blockIdx.x * 1024 + tid;
  int x = (idx < N_DST) ? counts[idx] : 0;
  int incl = x;
#pragma unroll
  for (int o = 1; o < 64; o <<= 1) {
    int y = __shfl_up(incl, o);
    if (lane >= o) incl += y;
  }
  if (lane == 63) wpart[wid] = incl;
  __syncthreads();
  if (wid == 0) {
    int v = (lane < 16) ? wpart[lane] : 0;
    int s = v;
#pragma unroll
    for (int o = 1; o < 16; o <<= 1) {
      int y = __shfl_up(s, o);
      if (lane >= o) s += y;
    }
    if (lane < 16) wpart[lane] = s;
  }
  __syncthreads();
  int woff = (wid > 0) ? wpart[wid - 1] : 0;
  int v = boff[blockIdx.x] + woff + incl - x;
  if (idx < N_DST) {
    offs[idx] = v;
    cursor[idx] = v;
  }
  if (idx == N_DST - 1) offs[N_DST] = v + x;
}

// dst-sorted edge list: elist[p] = e, dsts[p] = dst
__global__ __launch_bounds__(256) void fill_kernel(const int* __restrict__ dsti,
    int* __restrict__ cursor, int* __restrict__ elist, int* __restrict__ dsts) {
  int e = blockIdx.x * 256 + threadIdx.x;
  if (e < E_NUM) {
    int d = dsti[e];
    int p = atomicAdd(&cursor[d], 1);
    elist[p] = e;
    dsts[p] = d;
  }
}

// pinned counted-vmcnt wait (rule #18: sched_barrier after, so MFMAs can't hoist above)
#define WAITV(N) do { \
    asm volatile("s_waitcnt vmcnt(" #N ")" ::: "memory"); \
    __builtin_amdgcn_sched_barrier(0); } while (0)
// raw barrier that does NOT drain vmcnt (unlike __syncthreads): only LDS ops ordered
#define PIPE_BAR() do { \
    asm volatile("s_waitcnt lgkmcnt(0)" ::: "memory"); \
    __builtin_amdgcn_sched_barrier(0); \
    __builtin_amdgcn_s_barrier(); \
    __builtin_amdgcn_sched_barrier(0); } while (0)

// ====== KV kernel: all-asm VMEM, FIFO-counted vmcnt, 2-deep staging pipeline ======
// Sorted-gather dataflow (lowest traffic): block owns 64 dst-sorted edges; V/score
// written sequentially in sorted space; Q reads L1/L2-hot. Per phase the wave issues
// B(t) [8 asm L2 loads] THEN stage(t+2) [4 asm HBM loads]; vmcnt(4) retires exactly
// {older stage + B(t)} leaving the newest staging in flight ACROSS the raw barrier.
__global__ __launch_bounds__(256, 3) void kv_kernel(
    const float* __restrict__ node_h, const float* __restrict__ edge_f,
    const float* __restrict__ dtp, const float* __restrict__ tw, const float* __restrict__ tb,
    const __bf16* __restrict__ Bq,
    const float* __restrict__ bk, const float* __restrict__ bv,
    const int* __restrict__ elist, const int* __restrict__ dsts,
    const float* __restrict__ Qn,
    __bf16* __restrict__ Vout, float* __restrict__ score)
{
  __shared__ __align__(16) char Ab[2][8192];    // [2][64 rows][128 B] bf16, XOR-swizzled
  __shared__ __align__(16) char Vlds[16384];    // V bounce [64][256 B] bf16, swizzled
  __shared__ int Elds[64];
  __shared__ int Dlds[64];
  __shared__ float dts[64];
  __shared__ float twl[128];
  __shared__ float tbl[128];

  const int tid = threadIdx.x;
  const int e0 = blockIdx.x * 64;
  const int lane = tid & 63;
  const int w = tid >> 6;
  const int lrow = lane & 15;
  const int lk = lane >> 4;
  const int aswz = (lrow & 7) << 4;

  if (tid < 64) {
    int e = elist[e0 + tid];
    Elds[tid] = e;
    Dlds[tid] = dsts[e0 + tid];
    dts[tid] = dtp[e];
  } else if (tid < 192) {
    int j = tid - 64;
    twl[j] = tw[j];
    tbl[j] = tb[j];
  }
  __syncthreads();

  const int srow = tid >> 2;
  const int sq = tid & 3;
  const int eidx = Elds[srow];
  const char* sR = (const char*)(node_h + (size_t)(N_DST + eidx) * 128) + sq * 64;
  const char* eR = (const char*)(edge_f + (size_t)eidx * 128) + sq * 64;

  float4 sA0, sA1, sA2, sA3, sB0, sB1, sB2, sB3;
#define ISSUE_STAGE(S0, S1, S2, S3, T) do { \
    const char* _p = ((T) < 2) ? (sR + (T) * 256) : (eR + ((T) - 2) * 256); \
    asm volatile("global_load_dwordx4 %0, %4, off\n\t" \
                 "global_load_dwordx4 %1, %4, off offset:16\n\t" \
                 "global_load_dwordx4 %2, %4, off offset:32\n\t" \
                 "global_load_dwordx4 %3, %4, off offset:48" \
                 : "=&v"(S0), "=&v"(S1), "=&v"(S2), "=&v"(S3) : "v"(_p)); } while (0)

  auto writeAt = [&](char* buf, float4 v0, float4 v1, float4 v2, float4 v3) {
    char* rb = buf + srow * 128;
    int sw = (srow & 7) << 4;
    float4 vv[4] = {v0, v1, v2, v3};
#pragma unroll
    for (int i = 0; i < 4; ++i) {
      bf16x4 b;
      b[0]=(__bf16)vv[i].x; b[1]=(__bf16)vv[i].y; b[2]=(__bf16)vv[i].z; b[3]=(__bf16)vv[i].w;
      *reinterpret_cast<bf16x4*>(rb + ((sq * 32 + i * 8) ^ sw)) = b;
    }
  };

  const bf16x8* __restrict__ Bw = reinterpret_cast<const bf16x8*>(Bq) + (size_t)(w * 4) * 64 + lane;
  float4 bq0, bq1, bq2, bq3, bq4, bq5, bq6, bq7;
#define ISSUE_B4(B0, B1, B2, B3, K32) do { \
    const void* _p = (const void*)(Bw + (size_t)(K32) * 16 * 64); \
    asm volatile("global_load_dwordx4 %0, %4, off\n\t" \
                 "global_load_dwordx4 %1, %4, off offset:1024\n\t" \
                 "global_load_dwordx4 %2, %4, off offset:2048\n\t" \
                 "global_load_dwordx4 %3, %4, off offset:3072" \
                 : "=&v"(B0), "=&v"(B1), "=&v"(B2), "=&v"(B3) : "v"(_p)); } while (0)
#define ISSUE_B8(T) do { ISSUE_B4(bq0, bq1, bq2, bq3, (T) * 2); \
                         ISSUE_B4(bq4, bq5, bq6, bq7, (T) * 2 + 1); } while (0)

  f32x4 acc[4][4];
#pragma unroll
  for (int mf = 0; mf < 4; ++mf)
#pragma unroll
    for (int nf = 0; nf < 4; ++nf)
      acc[mf][nf] = (f32x4){0.f, 0.f, 0.f, 0.f};

  float dv[4];
#pragma unroll
  for (int mf = 0; mf < 4; ++mf) dv[mf] = dts[mf * 16 + lrow];

  auto mfmaTile = [&](const char* buf) {
#pragma unroll
    for (int ks = 0; ks < 2; ++ks) {
#pragma unroll
      for (int mf = 0; mf < 4; ++mf) {
        bf16x8 a = *reinterpret_cast<const bf16x8*>(
            buf + (mf * 16 + lrow) * 128 + ((ks * 64 + lk * 16) ^ aswz));
        acc[mf][0] = __builtin_amdgcn_mfma_f32_16x16x32_bf16(a, __builtin_bit_cast(bf16x8, ks ? bq4 : bq0), acc[mf][0], 0, 0, 0);
        acc[mf][1] = __builtin_amdgcn_mfma_f32_16x16x32_bf16(a, __builtin_bit_cast(bf16x8, ks ? bq5 : bq1), acc[mf][1], 0, 0, 0);
        acc[mf][2] = __builtin_amdgcn_mfma_f32_16x16x32_bf16(a, __builtin_bit_cast(bf16x8, ks ? bq6 : bq2), acc[mf][2], 0, 0, 0);
        acc[mf][3] = __builtin_amdgcn_mfma_f32_16x16x32_bf16(a, __builtin_bit_cast(bf16x8, ks ? bq7 : bq3), acc[mf][3], 0, 0, 0);
      }
    }
  };

  // ---- prologue: 2-deep staging
  ISSUE_STAGE(sA0, sA1, sA2, sA3, 0);          // q: sA=4
  ISSUE_STAGE(sB0, sB1, sB2, sB3, 1);          // q: 8
  WAITV(4);                                    // sA(0) ready; stage(1) in flight
  writeAt(Ab[0], sA0, sA1, sA2, sA3);
  PIPE_BAR();
  // ---- phase 0 (tile0 in Ab0)
  ISSUE_B8(0);                                 // q: s1:4 + B:8 = 12
  ISSUE_STAGE(sA0, sA1, sA2, sA3, 2);          // q: 16
  WAITV(4);                                    // retires s1 + B0; stage(2) in flight
  mfmaTile(Ab[0]);
  writeAt(Ab[1], sB0, sB1, sB2, sB3);
  PIPE_BAR();
  // ---- phase 1 (tile1 in Ab1)
  ISSUE_B8(1);                                 // q: s2:4 + B:8
  ISSUE_STAGE(sB0, sB1, sB2, sB3, 3);          // q: 16
  WAITV(4);                                    // retires s2 + B1; stage(3) in flight
  mfmaTile(Ab[1]);
  writeAt(Ab[0], sA0, sA1, sA2, sA3);
  PIPE_BAR();
  // ---- phase 2 (tile2 in Ab0)
  ISSUE_B8(2);                                 // q: s3:4 + B:8
  WAITV(0);                                    // drains B2 (+s3, needed this phase anyway)
  mfmaTile(Ab[0]);
  writeAt(Ab[1], sB0, sB1, sB2, sB3);
  PIPE_BAR();
  // ---- phase 3 (tile3 in Ab1)
  ISSUE_B8(3);
  WAITV(0);
  mfmaTile(Ab[1]);

  // ---- time-cos K-steps: B one step ahead, cos VALU hides B latency
  ISSUE_B4(bq0, bq1, bq2, bq3, 8);
#pragma unroll
  for (int cs = 0; cs < 4; ++cs) {
    if (cs == 0) ISSUE_B4(bq4, bq5, bq6, bq7, 9);
    else if (cs == 1) ISSUE_B4(bq0, bq1, bq2, bq3, 10);
    else if (cs == 2) ISSUE_B4(bq4, bq5, bq6, bq7, 11);
    int J = cs * 32 + lk * 8;
    f32x4 w0 = *reinterpret_cast<const f32x4*>(twl + J);
    f32x4 w1 = *reinterpret_cast<const f32x4*>(twl + J + 4);
    f32x4 c0 = *reinterpret_cast<const f32x4*>(tbl + J);
    f32x4 c1 = *reinterpret_cast<const f32x4*>(tbl + J + 4);
    bf16x8 a[4];
#pragma unroll
    for (int mf = 0; mf < 4; ++mf) {
      float d = dv[mf];
#pragma unroll
      for (int j = 0; j < 4; ++j) {
        a[mf][j] = (__bf16)fast_cos(d * w0[j] + c0[j]);
        a[mf][4 + j] = (__bf16)fast_cos(d * w1[j] + c1[j]);
      }
    }
    if (cs < 3) { WAITV(4); } else { WAITV(0); }
    bool lo = !(cs & 1);
    bf16x8 b0 = __builtin_bit_cast(bf16x8, lo ? bq0 : bq4);
    bf16x8 b1 = __builtin_bit_cast(bf16x8, lo ? bq1 : bq5);
    bf16x8 b2 = __builtin_bit_cast(bf16x8, lo ? bq2 : bq6);
    bf16x8 b3 = __builtin_bit_cast(bf16x8, lo ? bq3 : bq7);
#pragma unroll
    for (int mf = 0; mf < 4; ++mf) {
      acc[mf][0] = __builtin_amdgcn_mfma_f32_16x16x32_bf16(a[mf], b0, acc[mf][0], 0, 0, 0);
      acc[mf][1] = __builtin_amdgcn_mfma_f32_16x16x32_bf16(a[mf], b1, acc[mf][1], 0, 0, 0);
      acc[mf][2] = __builtin_amdgcn_mfma_f32_16x16x32_bf16(a[mf], b2, acc[mf][2], 0, 0, 0);
      acc[mf][3] = __builtin_amdgcn_mfma_f32_16x16x32_bf16(a[mf], b3, acc[mf][3], 0, 0, 0);
    }
  }

  // ---- epilogue: scores from regs (waves 0,1; Q L1/L2-hot), V bounce (waves 2,3)
  if (w >= 2) {
#pragma unroll
    for (int nf = 0; nf < 4; ++nf) {
      int vcol = (w - 2) * 64 + nf * 16 + lrow;
      float bb = bv[vcol];
#pragma unroll
      for (int mf = 0; mf < 4; ++mf) {
#pragma unroll
        for (int r = 0; r < 4; ++r) {
          int row = mf * 16 + lk * 4 + r;
          *reinterpret_cast<__bf16*>(Vlds + row * 256 + ((vcol * 2) ^ ((row & 7) << 4))) =
              (__bf16)(acc[mf][nf][r] + bb);
        }
      }
    }
  } else {
    float bkv[4];
#pragma unroll
    for (int nf = 0; nf < 4; ++nf) bkv[nf] = bk[w * 64 + nf * 16 + lrow];
#pragma unroll
    for (int mf = 0; mf < 4; ++mf) {
#pragma unroll
      for (int r = 0; r < 4; ++r) {
        int row = mf * 16 + lk * 4 + r;
        const float* qrow = Qn + ((size_t)Dlds[row] << 7) + w * 64;
        float s = 0.f;
#pragma unroll
        for (int nf = 0; nf < 4; ++nf)
          s += (acc[mf][nf][r] + bkv[nf]) * qrow[nf * 16 + lrow];
        s += __shfl_xor(s, 1);
        s += __shfl_xor(s, 2);
        s += __shfl_xor(s, 4);
        s += __shfl_xor(s, 8);
        if (lrow == 0) {
          s = (s >= 0.f) ? s : 0.2f * s;
          score[((size_t)(e0 + row) << 1) + w] = s;
        }
      }
    }
  }
  __syncthreads();
#pragma unroll
  for (int i = 0; i < 4; ++i) {
    int c = tid + i * 256;
    int r = c >> 4, cb = (c & 15) << 4;
    bf16x8 vv = *reinterpret_cast<const bf16x8*>(Vlds + r * 256 + (cb ^ ((r & 7) << 4)));
    *reinterpret_cast<bf16x8*>(Vout + (((size_t)(e0 + r)) << 7) + (c & 15) * 8) = vv;
  }
}

// ---------------- MFMA GEMM (modes 0, 2), bf16 LDS staging ----------------
// MODE 0: Qn = tgt @ Wq1^T + cq                 (K=128)
// MODE 2: out = LN(relu([h|tgt] @ Wout^T+bout)) (K=256; dtp=gamma, tw=beta)
template<int MODE>
__global__ __launch_bounds__(256, 4) void gemm_kernel(
    const float* __restrict__ A0, const float* __restrict__ A1,
    const float* __restrict__ dtp, const float* __restrict__ tw,
    const __bf16* __restrict__ Bq, const float* __restrict__ bias0,
    float* __restrict__ outF)
{
  constexpr int NC = 128;
  constexpr int NFRAGW = 2;
  __shared__ __align__(16) char Abuf[2][64 * 256];

  const int tid = threadIdx.x;
  const int e0 = blockIdx.x * 64;
  const int nv = min(64, N_DST - e0);
  const int srow = tid >> 5;
  const int sc4 = (tid & 31) << 2;

  const int lane = tid & 63;
  const int w = tid >> 6;
  const int nbase = w * (NC / 4);
  const int lrow = lane & 15;
  const int lk = lane >> 4;
  const int aswz = (lrow & 7) << 4;
  const bf16x8* __restrict__ Bw =
      reinterpret_cast<const bf16x8*>(Bq) + (size_t)(w * NFRAGW) * 64 + lane;

  f32x4 acc[4][NFRAGW];
#pragma unroll
  for (int mf = 0; mf < 4; ++mf)
#pragma unroll
    for (int nf = 0; nf < NFRAGW; ++nf)
      acc[mf][nf] = (f32x4){0.f, 0.f, 0.f, 0.f};

  auto issueA = [&](int t, float4 (&v)[8]) {
    const float* base = (t == 0) ? A0 : A1;
#pragma unroll
    for (int i = 0; i < 8; ++i) {
      int r = srow + i * 8;
      v[i] = (r < nv) ? *reinterpret_cast<const float4*>(base + (size_t)(e0 + r) * 128 + sc4)
                      : make_float4(0.f, 0.f, 0.f, 0.f);
    }
  };
  auto writeA = [&](char* buf, float4 (&v)[8]) {
#pragma unroll
    for (int i = 0; i < 8; ++i) {
      int r = srow + i * 8;
      bf16x4 b;
      b[0]=(__bf16)v[i].x; b[1]=(__bf16)v[i].y; b[2]=(__bf16)v[i].z; b[3]=(__bf16)v[i].w;
      *reinterpret_cast<bf16x4*>(buf + r * 256 + ((sc4 * 2) ^ ((r & 7) << 4))) = b;
    }
  };
  auto ktile = [&](const char* buf, int t) {
#pragma unroll
    for (int ks = 0; ks < 4; ++ks) {
      bf16x8 b[NFRAGW];
#pragma unroll
      for (int nf = 0; nf < NFRAGW; ++nf)
        b[nf] = Bw[((size_t)(t * 4 + ks) * 4 * NFRAGW + nf) * 64];
      bf16x8 a[4];
#pragma unroll
      for (int mf = 0; mf < 4; ++mf)
        a[mf] = *reinterpret_cast<const bf16x8*>(
            buf + (mf * 16 + lrow) * 256 + (((ks * 32 + lk * 8) * 2) ^ aswz));
#pragma unroll
      for (int nf = 0; nf < NFRAGW; ++nf)
#pragma unroll
        for (int mf = 0; mf < 4; ++mf)
          acc[mf][nf] = __builtin_amdgcn_mfma_f32_16x16x32_bf16(a[mf], b[nf], acc[mf][nf], 0, 0, 0);
    }
  };

  float4 v[8];
  issueA(0, v);
  writeA(Abuf[0], v);
  __syncthreads();
  if constexpr (MODE == 2) {
    issueA(1, v);
    ktile(Abuf[0], 0);
    writeA(Abuf[1], v);
    __syncthreads();
    ktile(Abuf[1], 1);
  } else {
    ktile(Abuf[0], 0);
  }

  if constexpr (MODE == 0) {
#pragma unroll
    for (int nf = 0; nf < NFRAGW; ++nf) {
      int col = nbase + nf * 16 + lrow;
      float bb = bias0[col];
#pragma unroll
      for (int mf = 0; mf < 4; ++mf) {
#pragma unroll
        for (int r = 0; r < 4; ++r) {
          int row = mf * 16 + lk * 4 + r;
          if (row < nv)
            outF[(size_t)(e0 + row) * 128 + col] = acc[mf][nf][r] + bb;
        }
      }
    }
  } else {
    // fused relu + layernorm epilogue
    const float* gammaP = dtp;
    const float* betaP = tw;
    float vals[NFRAGW][4][4];
#pragma unroll
    for (int nf = 0; nf < NFRAGW; ++nf) {
      float bb = bias0[nbase + nf * 16 + lrow];
#pragma unroll
      for (int mf = 0; mf < 4; ++mf)
#pragma unroll
        for (int r = 0; r < 4; ++r)
          vals[nf][mf][r] = fmaxf(acc[mf][nf][r] + bb, 0.f);
    }
    __syncthreads();
    float* sums = reinterpret_cast<float*>(Abuf[0]);
    float* sqs  = reinterpret_cast<float*>(Abuf[0]) + 256;
    float* stats = reinterpret_cast<float*>(Abuf[0]) + 512;
#pragma unroll
    for (int mf = 0; mf < 4; ++mf) {
#pragma unroll
      for (int r = 0; r < 4; ++r) {
        float s1 = vals[0][mf][r] + vals[1][mf][r];
        float s2 = vals[0][mf][r] * vals[0][mf][r] + vals[1][mf][r] * vals[1][mf][r];
#pragma unroll
        for (int o = 1; o < 16; o <<= 1) {
          s1 += __shfl_xor(s1, o);
          s2 += __shfl_xor(s2, o);
        }
        if (lrow == 0) {
          int row = mf * 16 + lk * 4 + r;
          sums[w * 64 + row] = s1;
          sqs[w * 64 + row] = s2;
        }
      }
    }
    __syncthreads();
    if (tid < 64) {
      float s = sums[tid] + sums[64 + tid] + sums[128 + tid] + sums[192 + tid];
      float q = sqs[tid] + sqs[64 + tid] + sqs[128 + tid] + sqs[192 + tid];
      float mean = s * (1.f / 128.f);
      float var = q * (1.f / 128.f) - mean * mean;
      stats[tid * 2] = mean;
      stats[tid * 2 + 1] = rsqrtf(var + 1e-5f);
    }
    __syncthreads();
#pragma unroll
    for (int nf = 0; nf < NFRAGW; ++nf) {
      int col = nbase + nf * 16 + lrow;
      float g = gammaP[col], bC = betaP[col];
#pragma unroll
      for (int mf = 0; mf < 4; ++mf) {
#pragma unroll
        for (int r = 0; r < 4; ++r) {
          int row = mf * 16 + lk * 4 + r;
          if (row < nv) {
            float mean = stats[row * 2], rs = stats[row * 2 + 1];
            outF[(size_t)(e0 + row) * 128 + col] = (vals[nf][mf][r] - mean) * rs * g + bC;
          }
        }
      }
    }
  }
}

// ---------------- per-dst softmax + weighted V (sequential; 4 dst/block) ----------------
__global__ __launch_bounds__(256) void agg_kernel(const int* __restrict__ offs,
    const float* __restrict__ score, const __bf16* __restrict__ V, float* __restrict__ h) {
  int d = blockIdx.x * 4 + (threadIdx.x >> 6);
  if (d >= N_DST) return;
  int lane = threadIdx.x & 63;
  int beg = offs[d], end = offs[d + 1];
  int n = end - beg;
  float m0 = -3.0e38f, m1 = -3.0e38f;
  for (int i = lane; i < n; i += 64) {
    float2 sc = *reinterpret_cast<const float2*>(score + 2 * (size_t)(beg + i));
    m0 = fmaxf(m0, sc.x); m1 = fmaxf(m1, sc.y);
  }
#pragma unroll
  for (int o = 32; o; o >>= 1) {
    m0 = fmaxf(m0, __shfl_xor(m0, o));
    m1 = fmaxf(m1, __shfl_xor(m1, o));
  }
  float s0 = 0.f, s1 = 0.f;
  for (int i = lane; i < n; i += 64) {
    float2 sc = *reinterpret_cast<const float2*>(score + 2 * (size_t)(beg + i));
    s0 += __expf(sc.x - m0); s1 += __expf(sc.y - m1);
  }
#pragma unroll
  for (int o = 32; o; o >>= 1) {
    s0 += __shfl_xor(s0, o);
    s1 += __shfl_xor(s1, o);
  }
  float inv0 = (n > 0) ? 1.f / s0 : 0.f;
  float inv1 = (n > 0) ? 1.f / s1 : 0.f;
  int q = lane >> 4, j = lane & 15;
  int hsel = j >> 3;
  float acc[8];
#pragma unroll
  for (int k2 = 0; k2 < 8; ++k2) acc[k2] = 0.f;
  for (int i0 = 0; i0 < n; i0 += 4) {
    int i = i0 + q;
    if (i < n) {
      size_t p = beg + i;
      float2 sc = *reinterpret_cast<const float2*>(score + 2 * p);
      float wgt = hsel ? __expf(sc.y - m1) * inv1 : __expf(sc.x - m0) * inv0;
      bf16x8 v = *reinterpret_cast<const bf16x8*>(V + (p << 7) + j * 8);
#pragma unroll
      for (int k2 = 0; k2 < 8; ++k2) acc[k2] += wgt * (float)v[k2];
    }
  }
#pragma unroll
  for (int k2 = 0; k2 < 8; ++k2) {
    acc[k2] += __shfl_xor(acc[k2], 16);
    acc[k2] += __shfl_xor(acc[k2], 32);
  }
  if (q == 0) {
    float4 lo = make_float4(acc[0], acc[1], acc[2], acc[3]);
    float4 hi = make_float4(acc[4], acc[5], acc[6], acc[7]);
    float* dst = h + ((size_t)d << 7) + j * 8;
    *reinterpret_cast<float4*>(dst) = lo;
    *reinterpret_cast<float4*>(dst + 4) = hi;
  }
}

extern "C" void kernel_launch(void* const* d_in, const int* in_sizes, int n_in,
                              void* d_out, int out_size, void* d_ws, size_t ws_size,
                              hipStream_t stream) {
  (void)in_sizes; (void)n_in; (void)out_size; (void)ws_size;
  const float* node_h = (const float*)d_in[0];
  const float* edge_f = (const float*)d_in[1];
  const float* dtp    = (const float*)d_in[2];
  const int*   dsti   = (const int*)d_in[3];
  const float* tw     = (const float*)d_in[4];
  const float* tb     = (const float*)d_in[5];
  const float* Wq     = (const float*)d_in[6];
  const float* bq     = (const float*)d_in[7];
  const float* Wk     = (const float*)d_in[8];
  const float* bk     = (const float*)d_in[9];
  const float* Wv     = (const float*)d_in[10];
  const float* bv     = (const float*)d_in[11];
  const float* Wout   = (const float*)d_in[12];
  const float* bout   = (const float*)d_in[13];
  const float* gamma  = (const float*)d_in[14];
  const float* beta   = (const float*)d_in[15];
  float* outp = (float*)d_out;

  size_t off = 0;
  auto take = [&](size_t nbytes) -> void* {
    void* r = (char*)d_ws + off;
    off += (nbytes + 255) & ~(size_t)255;
    return r;
  };
  __bf16* Bq_kv  = (__bf16*)take((size_t)12288 * 16);
  __bf16* Bq_q   = (__bf16*)take((size_t)2048 * 16);
  __bf16* Bq_out = (__bf16*)take((size_t)4096 * 16);
  float*  cq     = (float*)take(128 * 4);
  float*  Qn     = (float*)take((size_t)N_DST * 128 * 4);
  __bf16* Vbuf   = (__bf16*)take((size_t)E_NUM * 128 * 2);
  float*  score  = (float*)take((size_t)E_NUM * 2 * 4);
  int*    counts = (int*)take((size_t)N_DST * 4);
  int*    offs   = (int*)take((size_t)(N_DST + 1) * 4);
  int*    cursor = (int*)take((size_t)N_DST * 4);
  int*    elist  = (int*)take((size_t)E_NUM * 4);
  int*    dsts   = (int*)take((size_t)E_NUM * 4);
  int*    bsum   = (int*)take(32 * 4);
  int*    boff   = (int*)take(32 * 4);
  float*  hbuf   = (float*)take((size_t)N_DST * 128 * 4);

  hipMemsetAsync(counts, 0, (size_t)N_DST * 4, stream);

  const int count_blocks = (E_NUM + 255) / 256;
  prep_kernel<<<1 + 48 + 8 + 16 + count_blocks, 256, 0, stream>>>(
      Wq, bq, tb, Wk, Wv, Wout, dsti, cq, Bq_kv, Bq_q, Bq_out, counts);

  gemm_kernel<0><<<(N_DST + 63) / 64, 256, 0, stream>>>(node_h, nullptr, nullptr, nullptr,
      Bq_q, cq, Qn);

  scanA_kernel<<<25, 1024, 0, stream>>>(counts, bsum);
  scanB_kernel<<<1, 64, 0, stream>>>(bsum, boff);
  scanC_kernel<<<25, 1024, 0, stream>>>(counts, boff, offs, cursor);
  fill_kernel<<<count_blocks, 256, 0, stream>>>(dsti, cursor, elist, dsts);

  kv_kernel<<<E_NUM / 64, 256, 0, stream>>>(node_h, edge_f, dtp, tw, tb,
      Bq_kv, bk, bv, elist, dsts, Qn, Vbuf, score);

  agg_kernel<<<(N_DST + 3) / 4, 256, 0, stream>>>(offs, score, Vbuf, hbuf);

  gemm_kernel<2><<<(N_DST + 63) / 64, 256, 0, stream>>>(hbuf, node_h, gamma, beta,
      Bq_out, bout, outp);
}